// Round 8
// baseline (880.082 us; speedup 1.0000x reference)
//
#include <hip/hip_runtime.h>
#include <hip/hip_bf16.h>
#include <math.h>

typedef __attribute__((ext_vector_type(8))) short bf16x8;
typedef __attribute__((ext_vector_type(4))) float f32x4;

#define R_TOTAL 8
#define CIN     256
#define COUT    256
#define HH      128
#define WW      128
#define BB      4
#define MTOT    (COUT * R_TOTAL)   // 2048
#define KTAPS   9

#define XRW   6                    // X window rows (4 outputs + halo)
#define XSZ   (XRW * 130 * 32)     // 24960 elems per X buffer (48.75 KB)
#define ABUF  (128 * 32)           // 4096 elems per A buffer (8 KB)

// ---------------------------------------------------------------------------
// async global->LDS, 16B per lane (lane l lands at base + l*16).
// ---------------------------------------------------------------------------
__device__ __forceinline__ void g2l16(void* lds, const void* g) {
    __builtin_amdgcn_global_load_lds(
        (const __attribute__((address_space(1))) unsigned int*)g,
        (__attribute__((address_space(3))) unsigned int*)lds,
        16, 0, 0);
}

// ---------------------------------------------------------------------------
// x (B,C,H,W) fp32 -> xb (B,H,W,C) bf16 (+ one appended zero row).
// ---------------------------------------------------------------------------
__global__ __launch_bounds__(256)
void to_nhwc_bf16(const float* __restrict__ x, __hip_bfloat16* __restrict__ xb) {
    __shared__ __hip_bfloat16 t[32][33];
    const int b  = blockIdx.z;
    const int c0 = blockIdx.y * 32;
    const int p0 = blockIdx.x * 32;
    const int tx = threadIdx.x & 31;
    const int ty = threadIdx.x >> 5;
    const float* xp = x + (size_t)b * CIN * (HH * WW);
    #pragma unroll
    for (int j = 0; j < 4; ++j) {
        int c = ty * 4 + j;
        t[c][tx] = __float2bfloat16(xp[(size_t)(c0 + c) * (HH * WW) + p0 + tx]);
    }
    __syncthreads();
    __hip_bfloat16* op = xb + ((size_t)b * (HH * WW) + p0) * CIN + c0;
    #pragma unroll
    for (int j = 0; j < 4; ++j) {
        int p = ty * 4 + j;
        op[(size_t)p * CIN + tx] = t[tx][p];
    }
}

__global__ __launch_bounds__(256)
void zero_guard_row(__hip_bfloat16* __restrict__ xb) {
    size_t base = (size_t)BB * HH * WW * CIN;
    int i = blockIdx.x * 256 + threadIdx.x;
    xb[base + i] = __float2bfloat16(0.0f);
}

// ---------------------------------------------------------------------------
// Rotate weights (fp32 math == jax affine_grid/grid_sample, align_corners=F,
// zero pad) -> rwb[m][tap][i] bf16, m = o*8 + r.
// ---------------------------------------------------------------------------
__global__ __launch_bounds__(256)
void rotate_weights_bf16(const float* __restrict__ w, __hip_bfloat16* __restrict__ rwb) {
    const int i = threadIdx.x;
    const int m = blockIdx.x;
    const int o = m >> 3, r = m & 7;

    float ang = 6.283185307179586f * (float)r / 8.0f;
    float cs = cosf(ang), sn = sinf(ang);

    const float* wp = w + ((size_t)o * CIN + i) * 9;
    __hip_bfloat16* op = rwb + (size_t)m * (KTAPS * CIN) + i;

    #pragma unroll
    for (int ky = 0; ky < 3; ++ky) {
        #pragma unroll
        for (int kx = 0; kx < 3; ++kx) {
            float yg = (2.0f * (float)ky + 1.0f) / 3.0f - 1.0f;
            float xg = (2.0f * (float)kx + 1.0f) / 3.0f - 1.0f;
            float xsf = cs * xg - sn * yg;
            float ysf = sn * xg + cs * yg;
            float ix = ((xsf + 1.0f) * 3.0f - 1.0f) * 0.5f;
            float iy = ((ysf + 1.0f) * 3.0f - 1.0f) * 0.5f;
            float ix0f = floorf(ix), iy0f = floorf(iy);
            float wx1 = ix - ix0f,  wy1 = iy - iy0f;
            float wx0 = 1.0f - wx1, wy0 = 1.0f - wy1;
            int ix0 = (int)ix0f, iy0 = (int)iy0f;
            int ix1 = ix0 + 1,   iy1 = iy0 + 1;
            float acc = 0.0f;
            if (iy0 >= 0 && iy0 < 3 && ix0 >= 0 && ix0 < 3) acc += wp[iy0*3+ix0] * (wy0*wx0);
            if (iy0 >= 0 && iy0 < 3 && ix1 >= 0 && ix1 < 3) acc += wp[iy0*3+ix1] * (wy0*wx1);
            if (iy1 >= 0 && iy1 < 3 && ix0 >= 0 && ix0 < 3) acc += wp[iy1*3+ix0] * (wy1*wx0);
            if (iy1 >= 0 && iy1 < 3 && ix1 >= 0 && ix1 < 3) acc += wp[iy1*3+ix1] * (wy1*wx1);
            op[(ky * 3 + kx) * CIN] = __float2bfloat16(acc);
        }
    }
}

// ---------------------------------------------------------------------------
// Main MFMA conv: 512 threads = 8 waves (2M x 4N), block tile 128M x 512N
// (four consecutive image rows; each wave owns one full output row, wave tile
// 64M x 128N -> 12 ds_read_b128 per 32 MFMA). K = 8 chunks(32ch) x 9 taps.
// Counted-vmcnt schedule: one raw s_barrier per tap, never drained in-loop.
// A: 4-buffered LDS (prefetch distance 2, 1 g2l/wave/tap).
// X: double-buffered 6-row window, 1 g2l/wave/tap at taps 1..6.
// Register budget: LDS (132 KB) pins 1 WG/CU = 2 waves/EU, so declare
// amdgpu_waves_per_eu(1,2) to let the allocator use up to the full unified
// file. R6/R7's (512,N) launch_bounds clamped to 128 VGPR -> acc alone filled
// the budget and ~880 MB/dispatch of scratch traffic throttled the kernel.
// ---------------------------------------------------------------------------
__global__ __attribute__((amdgpu_waves_per_eu(1, 2))) __launch_bounds__(512)
void rotconv_mfma_kernel(const __hip_bfloat16* __restrict__ xb,
                         const __hip_bfloat16* __restrict__ rwb,
                         float* __restrict__ out) {
    const int tid  = threadIdx.x;
    const int lane = tid & 63;
    const int w    = tid >> 6;        // 0..7
    const int wm   = w >> 2;          // 0..1
    const int wn   = w & 3;           // 0..3  (owns output row y0+wn)
    const int q    = lane >> 4, lr = lane & 15;

    // bijective XCD swizzle (2048 % 8 == 0): each XCD owns 2 m-panels
    const int bid = (blockIdx.x & 7) * 256 + (blockIdx.x >> 3);
    const int mt  = bid >> 7;         // 0..15
    const int nt  = bid & 127;        // 0..127
    const int b   = nt >> 5;          // 0..3
    const int y0  = (nt & 31) * 4;    // 0..124
    const int m0  = mt << 7;

    __shared__ __align__(16) __hip_bfloat16 xs[2 * XSZ];
    __shared__ __align__(16) __hip_bfloat16 As[4 * ABUF];

    // zero halo columns (colL = 0 and 129): 2 bufs x 6 rows x 2 cols x 32 ch
    for (int j = tid; j < 2 * XRW * 2 * 32; j += 512) {
        int bufi = j / (XRW * 2 * 32);
        int rem  = j % (XRW * 2 * 32);
        int row = rem / 64; int colsel = (rem >> 5) & 1; int ch = rem & 31;
        int colL = colsel ? 129 : 0;
        xs[bufi * XSZ + (row * 130 + colL) * 32 + ch] = __float2bfloat16(0.0f);
    }

    // ---- A read offsets (element units), slot-swizzled ----
    int aOff[4];
    #pragma unroll
    for (int mi = 0; mi < 4; ++mi) {
        int row = wm * 64 + mi * 16 + lr;
        aOff[mi] = row * 32 + 8 * (q ^ ((row >> 1) & 3));
    }
    // ---- B read offsets: window row wn (+ky at use), col = ni*16+lr+kx ----
    int bOff[8][3];
    #pragma unroll
    for (int ni = 0; ni < 8; ++ni)
        #pragma unroll
        for (int kx = 0; kx < 3; ++kx) {
            int colL = ni * 16 + lr + kx;            // 0..129
            bOff[ni][kx] = (wn * 130 + colL) * 32 + 8 * (q ^ ((colL >> 1) & 3));
        }

    // ---- A staging: wave w covers rows w*16..w*16+15 (1 g2l per wave) ----
    const int arow = w * 16 + (lane >> 2);
    const int dstA = (w * 16) * 32;                  // wave-uniform
    const __hip_bfloat16* srcA =
        rwb + (size_t)(m0 + arow) * (KTAPS * CIN) + 8 * ((lane & 3) ^ ((arow >> 1) & 3));

    // ---- X staging: 6 parts/wave: part j = window row j, colgroup w*16 ----
    const __hip_bfloat16* srcX[6];
    int dstX[6];
    #pragma unroll
    for (int j = 0; j < 6; ++j) {
        int gy = y0 - 1 + j;
        size_t rowIdx = ((unsigned)gy < (unsigned)HH) ? (size_t)(b * HH + gy)
                                                      : (size_t)(BB * HH);
        int gx = w * 16 + (lane >> 2);
        int colL = gx + 1;
        dstX[j] = (j * 130 + 1 + w * 16) * 32;       // wave-uniform
        srcX[j] = xb + (rowIdx * WW + gx) * CIN + 8 * ((lane & 3) ^ ((colL >> 1) & 3));
    }

    f32x4 acc[4][8];
    #pragma unroll
    for (int mi = 0; mi < 4; ++mi)
        #pragma unroll
        for (int ni = 0; ni < 8; ++ni) {
            f32x4 z = {0.f, 0.f, 0.f, 0.f};
            acc[mi][ni] = z;
        }

    __syncthreads();   // halo zeros visible

    // prologue: X(chunk0) parts 0..5, then A(k0), A(k1) — order pinned
    #pragma unroll
    for (int j = 0; j < 6; ++j) g2l16(xs + dstX[j], srcX[j]);
    __builtin_amdgcn_sched_barrier(0);
    g2l16(As + 0 * ABUF + dstA, srcA + 0 * CIN);
    __builtin_amdgcn_sched_barrier(0);
    g2l16(As + 1 * ABUF + dstA, srcA + 1 * CIN);

// ---- MFMA core for tap (chunk parity J, tap P): 4 A + 8 B reads, 32 MFMA
#define TAPCORE(J, P)                                                          \
    {                                                                          \
      const __hip_bfloat16* ar = As + (((J) + (P)) & 3) * ABUF;                \
      const __hip_bfloat16* br = xs + ((J) & 1) * XSZ + ((P) / 3) * (130*32);  \
      bf16x8 af[4];                                                            \
      _Pragma("unroll")                                                        \
      for (int mi = 0; mi < 4; ++mi) af[mi] = *(const bf16x8*)(ar + aOff[mi]); \
      _Pragma("unroll")                                                        \
      for (int h = 0; h < 2; ++h) {                                            \
        bf16x8 bv[4];                                                          \
        _Pragma("unroll")                                                      \
        for (int nj = 0; nj < 4; ++nj)                                         \
            bv[nj] = *(const bf16x8*)(br + bOff[h * 4 + nj][(P) % 3]);         \
        __builtin_amdgcn_s_setprio(1);                                         \
        _Pragma("unroll")                                                      \
        for (int mi = 0; mi < 4; ++mi)                                         \
          _Pragma("unroll")                                                    \
          for (int nj = 0; nj < 4; ++nj)                                       \
            acc[mi][h * 4 + nj] = __builtin_amdgcn_mfma_f32_16x16x32_bf16(     \
                af[mi], bv[nj], acc[mi][h * 4 + nj], 0, 0, 0);                 \
        __builtin_amdgcn_s_setprio(0);                                         \
      }                                                                        \
    }

// steady tap: issue A(g+2) [+ X part (P-1) of chunk c+1], counted wait, barrier
#define TAPS(J, P, NW, DOX)                                                    \
  {                                                                            \
    g2l16(As + (((J) + (P) + 2) & 3) * ABUF + dstA,                            \
          srcA + (((P) + 2) % 9) * CIN + (c + ((P) + 2) / 9) * 32);            \
    if (DOX) g2l16(xs + (((J) + 1) & 1) * XSZ + dstX[(P) ? (P) - 1 : 0],       \
                   srcX[(P) ? (P) - 1 : 0] + (c + 1) * 32);                    \
    asm volatile("s_waitcnt vmcnt(%0)" :: "i"(NW) : "memory");                 \
    asm volatile("s_barrier" ::: "memory");                                    \
    TAPCORE(J, P)                                                              \
  }

// tail tap (last chunk): A prefetch only while g+2 <= 71, no X
#define TAPT(J, P, NW)                                                         \
  {                                                                            \
    if ((P) <= 6)                                                              \
      g2l16(As + (((J) + (P) + 2) & 3) * ABUF + dstA,                          \
            srcA + (((P) + 2) % 9) * CIN + (c + ((P) + 2) / 9) * 32);          \
    asm volatile("s_waitcnt vmcnt(%0)" :: "i"(NW) : "memory");                 \
    asm volatile("s_barrier" ::: "memory");                                    \
    TAPCORE(J, P)                                                              \
  }

// order-robust vmcnt tables (X issued taps 1..6):
// steady: [2,3,4,4,4,4,4,3,2]   tail: [2,2,2,2,2,2,2,1,0]
#define CHKS(J)                                                                \
    TAPS(J, 0, 2, 0) TAPS(J, 1, 3, 1) TAPS(J, 2, 4, 1) TAPS(J, 3, 4, 1)        \
    TAPS(J, 4, 4, 1) TAPS(J, 5, 4, 1) TAPS(J, 6, 4, 1) TAPS(J, 7, 3, 0)        \
    TAPS(J, 8, 2, 0)

#define CHKT(J)                                                                \
    TAPT(J, 0, 2) TAPT(J, 1, 2) TAPT(J, 2, 2) TAPT(J, 3, 2) TAPT(J, 4, 2)      \
    TAPT(J, 5, 2) TAPT(J, 6, 2) TAPT(J, 7, 1) TAPT(J, 8, 0)

    for (int cb = 0; cb < 8; cb += 4) {
        { const int c = cb + 0; CHKS(0) }
        { const int c = cb + 1; CHKS(1) }
        { const int c = cb + 2; CHKS(2) }
        if (cb == 0) { const int c = 3; CHKS(3) }
        else         { const int c = 7; CHKT(3) }
    }

#undef TAPCORE
#undef TAPS
#undef TAPT
#undef CHKS
#undef CHKT

    // epilogue: max over 8 rotations (4 regs + quarter-swap), write fp32
    const int oBase = (m0 + wm * 64) >> 3;
    const int yOut  = y0 + wn;
    #pragma unroll
    for (int mi = 0; mi < 4; ++mi) {
        #pragma unroll
        for (int ni = 0; ni < 8; ++ni) {
            f32x4 a4 = acc[mi][ni];
            float v = fmaxf(fmaxf(a4[0], a4[1]), fmaxf(a4[2], a4[3]));
            v = fmaxf(v, __shfl_xor(v, 16));
            if ((q & 1) == 0) {
                int o = oBase + mi * 2 + (q >> 1);
                int colc = ni * 16 + lr;
                out[(((size_t)(b * COUT + o)) * HH + yOut) * WW + colc] = v;
            }
        }
    }
}

// ===========================================================================
// Fallback fp32 path (round-0, known-correct) in case ws is too small.
// ===========================================================================
__global__ void rotate_weights_kernel(const float* __restrict__ w,
                                      float* __restrict__ rw,
                                      int r0, int rcount) {
    int idx = blockIdx.x * blockDim.x + threadIdx.x;
    int total = COUT * CIN * rcount;
    if (idx >= total) return;
    int rr = idx % rcount;
    int ii = (idx / rcount) % CIN;
    int oo = idx / (rcount * CIN);
    int r  = r0 + rr;
    float ang = 6.283185307179586f * (float)r / 8.0f;
    float cs = cosf(ang), sn = sinf(ang);
    const float* wp = w  + ((size_t)oo * CIN + ii) * 9;
    float*       op = rw + (((size_t)oo * CIN + ii) * rcount + rr) * 9;
    #pragma unroll
    for (int ky = 0; ky < 3; ++ky)
        #pragma unroll
        for (int kx = 0; kx < 3; ++kx) {
            float yg = (2.0f * ky + 1.0f) / 3.0f - 1.0f;
            float xg = (2.0f * kx + 1.0f) / 3.0f - 1.0f;
            float xsf = cs * xg - sn * yg;
            float ysf = sn * xg + cs * yg;
            float ix = ((xsf + 1.0f) * 3.0f - 1.0f) * 0.5f;
            float iy = ((ysf + 1.0f) * 3.0f - 1.0f) * 0.5f;
            float ix0f = floorf(ix), iy0f = floorf(iy);
            float wx1 = ix - ix0f,  wy1 = iy - iy0f;
            float wx0 = 1.0f - wx1, wy0 = 1.0f - wy1;
            int ix0 = (int)ix0f, iy0 = (int)iy0f;
            int ix1 = ix0 + 1,   iy1 = iy0 + 1;
            float acc = 0.0f;
            if (iy0 >= 0 && iy0 < 3 && ix0 >= 0 && ix0 < 3) acc += wp[iy0*3+ix0]*(wy0*wx0);
            if (iy0 >= 0 && iy0 < 3 && ix1 >= 0 && ix1 < 3) acc += wp[iy0*3+ix1]*(wy0*wx1);
            if (iy1 >= 0 && iy1 < 3 && ix0 >= 0 && ix0 < 3) acc += wp[iy1*3+ix0]*(wy1*wx0);
            if (iy1 >= 0 && iy1 < 3 && ix1 >= 0 && ix1 < 3) acc += wp[iy1*3+ix1]*(wy1*wx1);
            op[ky * 3 + kx] = acc;
        }
}

template <int RCOUNT>
__global__ __launch_bounds__(256)
void rotconv_max_kernel(const float* __restrict__ x,
                        const float* __restrict__ rw,
                        float* __restrict__ out,
                        int first) {
    const int tid = threadIdx.x;
    const int tx = tid & 15;
    const int ty = tid >> 4;
    const int x0 = blockIdx.x * 32;
    const int y0 = blockIdx.y * 32;
    const int o  = blockIdx.z % COUT;
    const int b  = blockIdx.z / COUT;
    __shared__ float xsm[34][36];
    float acc[RCOUNT][2][2];
    #pragma unroll
    for (int r = 0; r < RCOUNT; ++r)
        #pragma unroll
        for (int py = 0; py < 2; ++py)
            #pragma unroll
            for (int px = 0; px < 2; ++px) acc[r][py][px] = 0.0f;
    for (int i = 0; i < CIN; ++i) {
        __syncthreads();
        const float* xp = x + ((size_t)(b * CIN + i)) * (HH * WW);
        for (int idx = tid; idx < 34 * 34; idx += 256) {
            int row = idx / 34, col = idx - row * 34;
            int gy = y0 - 1 + row, gx = x0 - 1 + col;
            float v = 0.0f;
            if (gy >= 0 && gy < HH && gx >= 0 && gx < WW) v = xp[gy * WW + gx];
            xsm[row][col] = v;
        }
        __syncthreads();
        float xv[4][4];
        #pragma unroll
        for (int ry = 0; ry < 4; ++ry)
            #pragma unroll
            for (int cx = 0; cx < 4; ++cx) xv[ry][cx] = xsm[ty*2+ry][tx*2+cx];
        const float* wp = rw + ((size_t)(o * CIN + i)) * (RCOUNT * 9);
        #pragma unroll
        for (int r = 0; r < RCOUNT; ++r) {
            float wv[9];
            #pragma unroll
            for (int t2 = 0; t2 < 9; ++t2) wv[t2] = wp[r * 9 + t2];
            #pragma unroll
            for (int py = 0; py < 2; ++py)
                #pragma unroll
                for (int px = 0; px < 2; ++px) {
                    float a = acc[r][py][px];
                    #pragma unroll
                    for (int ky = 0; ky < 3; ++ky)
                        #pragma unroll
                        for (int kx = 0; kx < 3; ++kx)
                            a += xv[py+ky][px+kx] * wv[ky*3+kx];
                    acc[r][py][px] = a;
                }
        }
    }
    #pragma unroll
    for (int py = 0; py < 2; ++py)
        #pragma unroll
        for (int px = 0; px < 2; ++px) {
            float m = acc[0][py][px];
            #pragma unroll
            for (int r = 1; r < RCOUNT; ++r) m = fmaxf(m, acc[r][py][px]);
            int oy = y0 + ty * 2 + py;
            int ox = x0 + tx * 2 + px;
            float* op = out + (((size_t)(b * COUT + o)) * HH + oy) * WW + ox;
            if (first) *op = m;
            else       *op = fmaxf(*op, m);
        }
}

// ===========================================================================
extern "C" void kernel_launch(void* const* d_in, const int* in_sizes, int n_in,
                              void* d_out, int out_size, void* d_ws, size_t ws_size,
                              hipStream_t stream) {
    const float* x = (const float*)d_in[0];
    const float* w = (const float*)d_in[1];
    float* out = (float*)d_out;

    const size_t xbBytes = ((size_t)BB * HH * WW + WW) * CIN * sizeof(__hip_bfloat16); // +1 zero row
    const size_t rwBytes = (size_t)MTOT * KTAPS * CIN * sizeof(__hip_bfloat16);

    if (ws_size >= xbBytes + rwBytes) {
        __hip_bfloat16* xbuf = (__hip_bfloat16*)d_ws;
        __hip_bfloat16* rwb  = (__hip_bfloat16*)((char*)d_ws + xbBytes);

        to_nhwc_bf16<<<dim3((HH * WW) / 32, CIN / 32, BB), 256, 0, stream>>>(x, xbuf);
        zero_guard_row<<<(WW * CIN) / 256, 256, 0, stream>>>(xbuf);
        rotate_weights_bf16<<<MTOT, 256, 0, stream>>>(w, rwb);
        rotconv_mfma_kernel<<<2048, 512, 0, stream>>>(xbuf, rwb, out);
        return;
    }

    // ---- fallback fp32 path ----
    float* rw = (float*)d_ws;
    int chunk = 8;
    while (chunk > 1 && (size_t)COUT * CIN * chunk * 9 * sizeof(float) > ws_size)
        chunk >>= 1;
    int first = 1;
    for (int r0 = 0; r0 < R_TOTAL; r0 += chunk) {
        int rc = chunk;
        int total = COUT * CIN * rc;
        rotate_weights_kernel<<<(total + 255) / 256, 256, 0, stream>>>(w, rw, r0, rc);
        dim3 grid(WW / 32, HH / 32, BB * COUT);
        switch (rc) {
            case 8: rotconv_max_kernel<8><<<grid, 256, 0, stream>>>(x, rw, out, first); break;
            case 4: rotconv_max_kernel<4><<<grid, 256, 0, stream>>>(x, rw, out, first); break;
            case 2: rotconv_max_kernel<2><<<grid, 256, 0, stream>>>(x, rw, out, first); break;
            default: rotconv_max_kernel<1><<<grid, 256, 0, stream>>>(x, rw, out, first); break;
        }
        first = 0;
    }
}

// Round 9
// 606.381 us; speedup vs baseline: 1.4514x; 1.4514x over previous
//
#include <hip/hip_runtime.h>
#include <hip/hip_bf16.h>
#include <math.h>

typedef __attribute__((ext_vector_type(8))) short bf16x8;
typedef __attribute__((ext_vector_type(4))) float f32x4;

#define R_TOTAL 8
#define CIN     256
#define COUT    256
#define HH      128
#define WW      128
#define BB      4
#define MTOT    (COUT * R_TOTAL)   // 2048
#define KTAPS   9

#define XSZ   (3 * 130 * 32)       // 12480 elems per X buffer (24.375 KB)
#define ABUF  (128 * 32)           // 4096 elems per A buffer (8 KB)

// ---------------------------------------------------------------------------
// async global->LDS, 16B per lane (lane l lands at base + l*16).
// ---------------------------------------------------------------------------
__device__ __forceinline__ void g2l16(void* lds, const void* g) {
    __builtin_amdgcn_global_load_lds(
        (const __attribute__((address_space(1))) unsigned int*)g,
        (__attribute__((address_space(3))) unsigned int*)lds,
        16, 0, 0);
}

// ---------------------------------------------------------------------------
// x (B,C,H,W) fp32 -> xb (B,H,W,C) bf16 (+ one appended zero row).
// ---------------------------------------------------------------------------
__global__ __launch_bounds__(256)
void to_nhwc_bf16(const float* __restrict__ x, __hip_bfloat16* __restrict__ xb) {
    __shared__ __hip_bfloat16 t[32][33];
    const int b  = blockIdx.z;
    const int c0 = blockIdx.y * 32;
    const int p0 = blockIdx.x * 32;
    const int tx = threadIdx.x & 31;
    const int ty = threadIdx.x >> 5;
    const float* xp = x + (size_t)b * CIN * (HH * WW);
    #pragma unroll
    for (int j = 0; j < 4; ++j) {
        int c = ty * 4 + j;
        t[c][tx] = __float2bfloat16(xp[(size_t)(c0 + c) * (HH * WW) + p0 + tx]);
    }
    __syncthreads();
    __hip_bfloat16* op = xb + ((size_t)b * (HH * WW) + p0) * CIN + c0;
    #pragma unroll
    for (int j = 0; j < 4; ++j) {
        int p = ty * 4 + j;
        op[(size_t)p * CIN + tx] = t[tx][p];
    }
}

__global__ __launch_bounds__(256)
void zero_guard_row(__hip_bfloat16* __restrict__ xb) {
    size_t base = (size_t)BB * HH * WW * CIN;
    int i = blockIdx.x * 256 + threadIdx.x;
    xb[base + i] = __float2bfloat16(0.0f);
}

// ---------------------------------------------------------------------------
// Rotate weights (fp32 math == jax affine_grid/grid_sample, align_corners=F,
// zero pad) -> rwb[m][tap][i] bf16, m = o*8 + r.
// ---------------------------------------------------------------------------
__global__ __launch_bounds__(256)
void rotate_weights_bf16(const float* __restrict__ w, __hip_bfloat16* __restrict__ rwb) {
    const int i = threadIdx.x;
    const int m = blockIdx.x;
    const int o = m >> 3, r = m & 7;

    float ang = 6.283185307179586f * (float)r / 8.0f;
    float cs = cosf(ang), sn = sinf(ang);

    const float* wp = w + ((size_t)o * CIN + i) * 9;
    __hip_bfloat16* op = rwb + (size_t)m * (KTAPS * CIN) + i;

    #pragma unroll
    for (int ky = 0; ky < 3; ++ky) {
        #pragma unroll
        for (int kx = 0; kx < 3; ++kx) {
            float yg = (2.0f * (float)ky + 1.0f) / 3.0f - 1.0f;
            float xg = (2.0f * (float)kx + 1.0f) / 3.0f - 1.0f;
            float xsf = cs * xg - sn * yg;
            float ysf = sn * xg + cs * yg;
            float ix = ((xsf + 1.0f) * 3.0f - 1.0f) * 0.5f;
            float iy = ((ysf + 1.0f) * 3.0f - 1.0f) * 0.5f;
            float ix0f = floorf(ix), iy0f = floorf(iy);
            float wx1 = ix - ix0f,  wy1 = iy - iy0f;
            float wx0 = 1.0f - wx1, wy0 = 1.0f - wy1;
            int ix0 = (int)ix0f, iy0 = (int)iy0f;
            int ix1 = ix0 + 1,   iy1 = iy0 + 1;
            float acc = 0.0f;
            if (iy0 >= 0 && iy0 < 3 && ix0 >= 0 && ix0 < 3) acc += wp[iy0*3+ix0] * (wy0*wx0);
            if (iy0 >= 0 && iy0 < 3 && ix1 >= 0 && ix1 < 3) acc += wp[iy0*3+ix1] * (wy0*wx1);
            if (iy1 >= 0 && iy1 < 3 && ix0 >= 0 && ix0 < 3) acc += wp[iy1*3+ix0] * (wy1*wx0);
            if (iy1 >= 0 && iy1 < 3 && ix1 >= 0 && ix1 < 3) acc += wp[iy1*3+ix1] * (wy1*wx1);
            op[(ky * 3 + kx) * CIN] = __float2bfloat16(acc);
        }
    }
}

// ---------------------------------------------------------------------------
// Main MFMA conv: 256 threads = 4 waves (2M x 2N), block tile 128M x 128N
// (one image row), wave tile 64x64. K = 8 chunks(32ch) x 9 taps.
// LDS 72.8 KB -> 2 blocks/CU (cross-block overlap hides barrier stalls).
// Frag pipelining: phase t ds-reads tap-(t+1) fragments into the alternate
// register set; tap-t MFMAs consume registers read last phase (no lgkm wait
// on the critical path). A 3-buffered LDS (slot = p%3, distance 2); X 3-row
// window double-buffered, 6 parts/wave at taps 1..6. Counted vmcnt, one raw
// s_barrier per tap, never drained in-loop.
// ---------------------------------------------------------------------------
__global__ __launch_bounds__(256)
void rotconv_mfma_kernel(const __hip_bfloat16* __restrict__ xb,
                         const __hip_bfloat16* __restrict__ rwb,
                         float* __restrict__ out) {
    const int tid  = threadIdx.x;
    const int lane = tid & 63;
    const int w    = tid >> 6;        // 0..3
    const int wm   = w >> 1;          // 0..1
    const int wn   = w & 1;           // 0..1
    const int q    = lane >> 4, lr = lane & 15;

    // bijective XCD swizzle (8192 % 8 == 0), m-major for A-panel L2 reuse
    const int bid = (blockIdx.x & 7) * 1024 + (blockIdx.x >> 3);
    const int mt  = bid >> 9;         // 0..15
    const int nt  = bid & 511;        // 0..511
    const int b   = nt >> 7;          // 0..3
    const int y0  = nt & 127;         // 0..127
    const int m0  = mt << 7;

    __shared__ __align__(16) __hip_bfloat16 xs[2 * XSZ];
    __shared__ __align__(16) __hip_bfloat16 As[3 * ABUF];

    // zero halo columns (colL = 0 and 129): 2 bufs x 3 rows x 2 cols x 32 ch
    for (int j = tid; j < 384; j += 256) {
        int bufi = j / 192;
        int rem  = j % 192;
        int row = rem / 64; int colsel = (rem >> 5) & 1; int ch = rem & 31;
        int colL = colsel ? 129 : 0;
        xs[bufi * XSZ + (row * 130 + colL) * 32 + ch] = __float2bfloat16(0.0f);
    }

    // ---- A read offsets (element units), slot-swizzled ----
    int aOff[4];
    #pragma unroll
    for (int mi = 0; mi < 4; ++mi) {
        int row = wm * 64 + mi * 16 + lr;
        aOff[mi] = row * 32 + 8 * (q ^ ((row >> 1) & 3));
    }
    // ---- B read offsets: col = wn*64 + ni*16 + lr + kx (row base at use) ----
    int bOff[4][3];
    #pragma unroll
    for (int ni = 0; ni < 4; ++ni)
        #pragma unroll
        for (int kx = 0; kx < 3; ++kx) {
            int colL = wn * 64 + ni * 16 + lr + kx;     // 0..129
            bOff[ni][kx] = colL * 32 + 8 * (q ^ ((colL >> 1) & 3));
        }

    // ---- A staging: wave w covers rows w*32..w*32+31 (2 g2l per wave) ----
    const int arow0 = w * 32 + (lane >> 2);
    const int arow1 = w * 32 + 16 + (lane >> 2);
    const int dstA0 = (w * 32) * 32;                    // wave-uniform
    const int dstA1 = (w * 32 + 16) * 32;
    const __hip_bfloat16* srcA0 =
        rwb + (size_t)(m0 + arow0) * (KTAPS * CIN) + 8 * ((lane & 3) ^ ((arow0 >> 1) & 3));
    const __hip_bfloat16* srcA1 =
        rwb + (size_t)(m0 + arow1) * (KTAPS * CIN) + 8 * ((lane & 3) ^ ((arow1 >> 1) & 3));

    // ---- X staging: 6 parts/wave cover 3 rows x 8 col-groups ----
    const __hip_bfloat16* srcX[6];
    int dstX[6];
    #pragma unroll
    for (int j = 0; j < 6; ++j) {
        int id  = j * 4 + w;                 // 0..23
        int row = id >> 3;                   // 0..2
        int cg  = (id & 7) * 16;
        int gy  = y0 - 1 + row;
        size_t rowIdx = ((unsigned)gy < (unsigned)HH) ? (size_t)(b * HH + gy)
                                                      : (size_t)(BB * HH);
        int gx = cg + (lane >> 2);
        int colL = gx + 1;
        dstX[j] = (row * 130 + 1 + cg) * 32;            // wave-uniform
        srcX[j] = xb + (rowIdx * WW + gx) * CIN + 8 * ((lane & 3) ^ ((colL >> 1) & 3));
    }

    f32x4 acc[4][4];
    #pragma unroll
    for (int mi = 0; mi < 4; ++mi)
        #pragma unroll
        for (int ni = 0; ni < 4; ++ni) {
            f32x4 z = {0.f, 0.f, 0.f, 0.f};
            acc[mi][ni] = z;
        }

    __syncthreads();   // halo zeros visible

    // prologue: X(chunk0) parts 0..5; A(0)->slot0, A(1)->slot1; full drain.
    #pragma unroll
    for (int j = 0; j < 6; ++j) g2l16(xs + dstX[j], srcX[j]);
    g2l16(As + 0 * ABUF + dstA0, srcA0 + 0 * CIN);
    g2l16(As + 0 * ABUF + dstA1, srcA1 + 0 * CIN);
    g2l16(As + 1 * ABUF + dstA0, srcA0 + 1 * CIN);
    g2l16(As + 1 * ABUF + dstA1, srcA1 + 1 * CIN);
    asm volatile("s_waitcnt vmcnt(0)" ::: "memory");
    __syncthreads();

    // fragment register double-buffer (all names static -> no scratch)
    bf16x8 af0[4], bv0[4], af1[4], bv1[4];
    {   // frags for tap 0: A slot 0, X buf 0, row 0, kx 0
        const __hip_bfloat16* ar = As;
        const __hip_bfloat16* br = xs;
        #pragma unroll
        for (int mi = 0; mi < 4; ++mi) af0[mi] = *(const bf16x8*)(ar + aOff[mi]);
        #pragma unroll
        for (int ni = 0; ni < 4; ++ni) bv0[ni] = *(const bf16x8*)(br + bOff[ni][0]);
    }

// ---- one phase (tap t = 9c+P): issue A(t+2) [+ X part P-1 for c+1], counted
//      wait (ensures A(t+1) landed), barrier, ds-read frags(t+1) into R-set,
//      16 MFMA consuming C-set (registers only). Slots: A(t) at p%3.
#define TAP(P, NW, DOA, DOX, DORD, XW, XR, CAf, CBv, RAf, RBv)                 \
  {                                                                            \
    if (DOA) {                                                                 \
      const int aofs = (((P) + 2) < 9) ? (((P) + 2) * CIN + c * 32)            \
                                       : ((((P) + 2) - 9) * CIN + (c + 1) * 32);\
      __hip_bfloat16* ab = As + (((P) + 2) % 3) * ABUF;                        \
      g2l16(ab + dstA0, srcA0 + aofs);                                         \
      g2l16(ab + dstA1, srcA1 + aofs);                                         \
    }                                                                          \
    if (DOX) g2l16(xs + (XW) * XSZ + dstX[(P) > 0 ? (P) - 1 : 0],              \
                   srcX[(P) > 0 ? (P) - 1 : 0] + (c + 1) * 32);                \
    asm volatile("s_waitcnt vmcnt(%0)" :: "i"(NW) : "memory");                 \
    asm volatile("s_barrier" ::: "memory");                                    \
    if (DORD) {                                                                \
      const __hip_bfloat16* ar = As + ((((P) + 1) % 3)) * ABUF;                \
      const __hip_bfloat16* br = xs + (XR) * XSZ                               \
                                 + (((((P) + 1) % 9)) / 3) * (130 * 32);       \
      _Pragma("unroll")                                                        \
      for (int mi = 0; mi < 4; ++mi) RAf[mi] = *(const bf16x8*)(ar + aOff[mi]);\
      _Pragma("unroll")                                                        \
      for (int ni = 0; ni < 4; ++ni)                                           \
          RBv[ni] = *(const bf16x8*)(br + bOff[ni][(((P) + 1) % 9) % 3]);      \
    }                                                                          \
    __builtin_amdgcn_s_setprio(1);                                             \
    _Pragma("unroll")                                                          \
    for (int mi = 0; mi < 4; ++mi)                                             \
      _Pragma("unroll")                                                        \
      for (int ni = 0; ni < 4; ++ni)                                           \
        acc[mi][ni] = __builtin_amdgcn_mfma_f32_16x16x32_bf16(                 \
            CAf[mi], CBv[ni], acc[mi][ni], 0, 0, 0);                           \
    __builtin_amdgcn_s_setprio(0);                                             \
  }

// steady vmcnt (order-robust min): [2,3,3,3,3,3,3,2,2]; tail: [2,...,2,0]
#define CHK0                                                                   \
    TAP(0, 2, 1, 0, 1, 1, 0, af0, bv0, af1, bv1)                               \
    TAP(1, 3, 1, 1, 1, 1, 0, af1, bv1, af0, bv0)                               \
    TAP(2, 3, 1, 1, 1, 1, 0, af0, bv0, af1, bv1)                               \
    TAP(3, 3, 1, 1, 1, 1, 0, af1, bv1, af0, bv0)                               \
    TAP(4, 3, 1, 1, 1, 1, 0, af0, bv0, af1, bv1)                               \
    TAP(5, 3, 1, 1, 1, 1, 0, af1, bv1, af0, bv0)                               \
    TAP(6, 3, 1, 1, 1, 1, 0, af0, bv0, af1, bv1)                               \
    TAP(7, 2, 1, 0, 1, 1, 0, af1, bv1, af0, bv0)                               \
    TAP(8, 2, 1, 0, 1, 1, 1, af0, bv0, af1, bv1)

#define CHK1                                                                   \
    TAP(0, 2, 1, 0, 1, 0, 1, af1, bv1, af0, bv0)                               \
    TAP(1, 3, 1, 1, 1, 0, 1, af0, bv0, af1, bv1)                               \
    TAP(2, 3, 1, 1, 1, 0, 1, af1, bv1, af0, bv0)                               \
    TAP(3, 3, 1, 1, 1, 0, 1, af0, bv0, af1, bv1)                               \
    TAP(4, 3, 1, 1, 1, 0, 1, af1, bv1, af0, bv0)                               \
    TAP(5, 3, 1, 1, 1, 0, 1, af0, bv0, af1, bv1)                               \
    TAP(6, 3, 1, 1, 1, 0, 1, af1, bv1, af0, bv0)                               \
    TAP(7, 2, 1, 0, 1, 0, 1, af0, bv0, af1, bv1)                               \
    TAP(8, 2, 1, 0, 1, 0, 0, af1, bv1, af0, bv0)

// tail chunk c=7 (J=1): no X, A issued while t+2 <= 71, last tap reads nothing
#define CHKT                                                                   \
    TAP(0, 2, 1, 0, 1, 0, 1, af1, bv1, af0, bv0)                               \
    TAP(1, 2, 1, 0, 1, 0, 1, af0, bv0, af1, bv1)                               \
    TAP(2, 2, 1, 0, 1, 0, 1, af1, bv1, af0, bv0)                               \
    TAP(3, 2, 1, 0, 1, 0, 1, af0, bv0, af1, bv1)                               \
    TAP(4, 2, 1, 0, 1, 0, 1, af1, bv1, af0, bv0)                               \
    TAP(5, 2, 1, 0, 1, 0, 1, af0, bv0, af1, bv1)                               \
    TAP(6, 2, 1, 0, 1, 0, 1, af1, bv1, af0, bv0)                               \
    TAP(7, 0, 0, 0, 1, 0, 1, af0, bv0, af1, bv1)                               \
    {                                                                          \
      __builtin_amdgcn_s_setprio(1);                                           \
      _Pragma("unroll")                                                        \
      for (int mi = 0; mi < 4; ++mi)                                           \
        _Pragma("unroll")                                                      \
        for (int ni = 0; ni < 4; ++ni)                                         \
          acc[mi][ni] = __builtin_amdgcn_mfma_f32_16x16x32_bf16(               \
              af1[mi], bv1[ni], acc[mi][ni], 0, 0, 0);                         \
      __builtin_amdgcn_s_setprio(0);                                           \
    }

    { const int c = 0; CHK0 }
    { const int c = 1; CHK1 }
    { const int c = 2; CHK0 }
    { const int c = 3; CHK1 }
    { const int c = 4; CHK0 }
    { const int c = 5; CHK1 }
    { const int c = 6; CHK0 }
    { const int c = 7; CHKT }

#undef TAP
#undef CHK0
#undef CHK1
#undef CHKT

    // epilogue: max over 8 rotations (4 regs + quarter-swap), write fp32
    const int oBase = (m0 + wm * 64) >> 3;
    #pragma unroll
    for (int mi = 0; mi < 4; ++mi) {
        #pragma unroll
        for (int ni = 0; ni < 4; ++ni) {
            f32x4 a4 = acc[mi][ni];
            float v = fmaxf(fmaxf(a4[0], a4[1]), fmaxf(a4[2], a4[3]));
            v = fmaxf(v, __shfl_xor(v, 16));
            if ((q & 1) == 0) {
                int o = oBase + mi * 2 + (q >> 1);
                int colc = wn * 64 + ni * 16 + lr;
                out[(((size_t)(b * COUT + o)) * HH + y0) * WW + colc] = v;
            }
        }
    }
}

// ===========================================================================
// Fallback fp32 path (round-0, known-correct) in case ws is too small.
// ===========================================================================
__global__ void rotate_weights_kernel(const float* __restrict__ w,
                                      float* __restrict__ rw,
                                      int r0, int rcount) {
    int idx = blockIdx.x * blockDim.x + threadIdx.x;
    int total = COUT * CIN * rcount;
    if (idx >= total) return;
    int rr = idx % rcount;
    int ii = (idx / rcount) % CIN;
    int oo = idx / (rcount * CIN);
    int r  = r0 + rr;
    float ang = 6.283185307179586f * (float)r / 8.0f;
    float cs = cosf(ang), sn = sinf(ang);
    const float* wp = w  + ((size_t)oo * CIN + ii) * 9;
    float*       op = rw + (((size_t)oo * CIN + ii) * rcount + rr) * 9;
    #pragma unroll
    for (int ky = 0; ky < 3; ++ky)
        #pragma unroll
        for (int kx = 0; kx < 3; ++kx) {
            float yg = (2.0f * ky + 1.0f) / 3.0f - 1.0f;
            float xg = (2.0f * kx + 1.0f) / 3.0f - 1.0f;
            float xsf = cs * xg - sn * yg;
            float ysf = sn * xg + cs * yg;
            float ix = ((xsf + 1.0f) * 3.0f - 1.0f) * 0.5f;
            float iy = ((ysf + 1.0f) * 3.0f - 1.0f) * 0.5f;
            float ix0f = floorf(ix), iy0f = floorf(iy);
            float wx1 = ix - ix0f,  wy1 = iy - iy0f;
            float wx0 = 1.0f - wx1, wy0 = 1.0f - wy1;
            int ix0 = (int)ix0f, iy0 = (int)iy0f;
            int ix1 = ix0 + 1,   iy1 = iy0 + 1;
            float acc = 0.0f;
            if (iy0 >= 0 && iy0 < 3 && ix0 >= 0 && ix0 < 3) acc += wp[iy0*3+ix0]*(wy0*wx0);
            if (iy0 >= 0 && iy0 < 3 && ix1 >= 0 && ix1 < 3) acc += wp[iy0*3+ix1]*(wy0*wx1);
            if (iy1 >= 0 && iy1 < 3 && ix0 >= 0 && ix0 < 3) acc += wp[iy1*3+ix0]*(wy1*wx0);
            if (iy1 >= 0 && iy1 < 3 && ix1 >= 0 && ix1 < 3) acc += wp[iy1*3+ix1]*(wy1*wx1);
            op[ky * 3 + kx] = acc;
        }
}

template <int RCOUNT>
__global__ __launch_bounds__(256)
void rotconv_max_kernel(const float* __restrict__ x,
                        const float* __restrict__ rw,
                        float* __restrict__ out,
                        int first) {
    const int tid = threadIdx.x;
    const int tx = tid & 15;
    const int ty = tid >> 4;
    const int x0 = blockIdx.x * 32;
    const int y0 = blockIdx.y * 32;
    const int o  = blockIdx.z % COUT;
    const int b  = blockIdx.z / COUT;
    __shared__ float xsm[34][36];
    float acc[RCOUNT][2][2];
    #pragma unroll
    for (int r = 0; r < RCOUNT; ++r)
        #pragma unroll
        for (int py = 0; py < 2; ++py)
            #pragma unroll
            for (int px = 0; px < 2; ++px) acc[r][py][px] = 0.0f;
    for (int i = 0; i < CIN; ++i) {
        __syncthreads();
        const float* xp = x + ((size_t)(b * CIN + i)) * (HH * WW);
        for (int idx = tid; idx < 34 * 34; idx += 256) {
            int row = idx / 34, col = idx - row * 34;
            int gy = y0 - 1 + row, gx = x0 - 1 + col;
            float v = 0.0f;
            if (gy >= 0 && gy < HH && gx >= 0 && gx < WW) v = xp[gy * WW + gx];
            xsm[row][col] = v;
        }
        __syncthreads();
        float xv[4][4];
        #pragma unroll
        for (int ry = 0; ry < 4; ++ry)
            #pragma unroll
            for (int cx = 0; cx < 4; ++cx) xv[ry][cx] = xsm[ty*2+ry][tx*2+cx];
        const float* wp = rw + ((size_t)(o * CIN + i)) * (RCOUNT * 9);
        #pragma unroll
        for (int r = 0; r < RCOUNT; ++r) {
            float wv[9];
            #pragma unroll
            for (int t2 = 0; t2 < 9; ++t2) wv[t2] = wp[r * 9 + t2];
            #pragma unroll
            for (int py = 0; py < 2; ++py)
                #pragma unroll
                for (int px = 0; px < 2; ++px) {
                    float a = acc[r][py][px];
                    #pragma unroll
                    for (int ky = 0; ky < 3; ++ky)
                        #pragma unroll
                        for (int kx = 0; kx < 3; ++kx)
                            a += xv[py+ky][px+kx] * wv[ky*3+kx];
                    acc[r][py][px] = a;
                }
        }
    }
    #pragma unroll
    for (int py = 0; py < 2; ++py)
        #pragma unroll
        for (int px = 0; px < 2; ++px) {
            float m = acc[0][py][px];
            #pragma unroll
            for (int r = 1; r < RCOUNT; ++r) m = fmaxf(m, acc[r][py][px]);
            int oy = y0 + ty * 2 + py;
            int ox = x0 + tx * 2 + px;
            float* op = out + (((size_t)(b * COUT + o)) * HH + oy) * WW + ox;
            if (first) *op = m;
            else       *op = fmaxf(*op, m);
        }
}

// ===========================================================================
extern "C" void kernel_launch(void* const* d_in, const int* in_sizes, int n_in,
                              void* d_out, int out_size, void* d_ws, size_t ws_size,
                              hipStream_t stream) {
    const float* x = (const float*)d_in[0];
    const float* w = (const float*)d_in[1];
    float* out = (float*)d_out;

    const size_t xbBytes = ((size_t)BB * HH * WW + WW) * CIN * sizeof(__hip_bfloat16); // +1 zero row
    const size_t rwBytes = (size_t)MTOT * KTAPS * CIN * sizeof(__hip_bfloat16);

    if (ws_size >= xbBytes + rwBytes) {
        __hip_bfloat16* xbuf = (__hip_bfloat16*)d_ws;
        __hip_bfloat16* rwb  = (__hip_bfloat16*)((char*)d_ws + xbBytes);

        to_nhwc_bf16<<<dim3((HH * WW) / 32, CIN / 32, BB), 256, 0, stream>>>(x, xbuf);
        zero_guard_row<<<(WW * CIN) / 256, 256, 0, stream>>>(w ? xbuf : xbuf);
        rotate_weights_bf16<<<MTOT, 256, 0, stream>>>(w, rwb);
        rotconv_mfma_kernel<<<8192, 256, 0, stream>>>(xbuf, rwb, out);
        return;
    }

    // ---- fallback fp32 path ----
    float* rw = (float*)d_ws;
    int chunk = 8;
    while (chunk > 1 && (size_t)COUT * CIN * chunk * 9 * sizeof(float) > ws_size)
        chunk >>= 1;
    int first = 1;
    for (int r0 = 0; r0 < R_TOTAL; r0 += chunk) {
        int rc = chunk;
        int total = COUT * CIN * rc;
        rotate_weights_kernel<<<(total + 255) / 256, 256, 0, stream>>>(w, rw, r0, rc);
        dim3 grid(WW / 32, HH / 32, BB * COUT);
        switch (rc) {
            case 8: rotconv_max_kernel<8><<<grid, 256, 0, stream>>>(x, rw, out, first); break;
            case 4: rotconv_max_kernel<4><<<grid, 256, 0, stream>>>(x, rw, out, first); break;
            case 2: rotconv_max_kernel<2><<<grid, 256, 0, stream>>>(x, rw, out, first); break;
            default: rotconv_max_kernel<1><<<grid, 256, 0, stream>>>(x, rw, out, first); break;
        }
        first = 0;
    }
}